// Round 2
// baseline (869.707 us; speedup 1.0000x reference)
//
#include <hip/hip_runtime.h>
#include <hip/hip_bf16.h>
#include <math.h>

// GraphAttentionLayer fused kernel v2, MI355X (gfx950).
//
// Math identity (see v1): row softmax of a row-constant logit collapses to
// 1/cnt over unmasked entries, so
//   out[n,m] = adj[n,m]>0 ? elu(h[n,m]/cnt[n]) : 0,  h = X @ W  (`a` unused)
// GEMM in split-bf16 (3 terms: XhWh + XhWl + XlWh) on the matrix pipe.
//
// v2 changes vs v1 (353us, MfmaUtil 18.8%, latency-bound):
//  - mfma_f32_32x32x16_bf16 (was 16x16x32): ~1.8x less LDS read traffic
//  - BM=128, 512 threads (8 waves, 4x2 wave grid), 127.5KB LDS, 1 block/CU
//  - 2-phase double-buffered pipeline: issue next-chunk X loads (regs) + B
//    global_load_lds BEFORE current MFMA, convert+ds_write AFTER (T14),
//    one barrier per chunk -> global latency hides under MFMA.

#define NROWS  200000
#define K_DIM  512
#define C_DIM  256
#define BM     128
#define BK     32
#define NCHUNK 16
#define LSTR   40                          // shorts per LDS row: 32 data + 8 pad = 80 B
#define CHUNK_BYTES (C_DIM * LSTR * 2)     // 20480 B per packed-W k-chunk per term
#define WPACK_BYTES (NCHUNK * CHUNK_BYTES) // 327680 B per term

typedef __bf16 bf16x8 __attribute__((ext_vector_type(8)));
typedef float  f32x4  __attribute__((ext_vector_type(4)));
typedef float  f32x16 __attribute__((ext_vector_type(16)));

// Pre-split + transpose W into LDS-image layout [chunk][col][k_local(+pad)].
__global__ void prep_w(const float* __restrict__ W,
                       __bf16* __restrict__ whi, __bf16* __restrict__ wlo) {
  int idx = blockIdx.x * 256 + threadIdx.x;   // = k*256 + c
  int k = idx >> 8, c = idx & 255;
  float w = W[idx];
  __bf16 h = (__bf16)w;
  __bf16 l = (__bf16)(w - (float)h);
  int off = ((k >> 5) * C_DIM + c) * LSTR + (k & 31);
  whi[off] = h;
  wlo[off] = l;
}

__device__ __forceinline__ void gload16(const void* g, void* l) {
  __builtin_amdgcn_global_load_lds(
      (const __attribute__((address_space(1))) unsigned*)g,
      (__attribute__((address_space(3))) unsigned*)l, 16, 0, 0);
}

__global__ void __launch_bounds__(512)
gat_kernel(const float* __restrict__ X, const int* __restrict__ adj,
           const __bf16* __restrict__ whi, const __bf16* __restrict__ wlo,
           float* __restrict__ out) {
  __shared__ __bf16 Ah[2][BM * LSTR];     // 2 x 10240 B
  __shared__ __bf16 Al[2][BM * LSTR];     // 2 x 10240 B
  __shared__ __bf16 Bh[2][C_DIM * LSTR];  // 2 x 20480 B
  __shared__ __bf16 Bl[2][C_DIM * LSTR];  // 2 x 20480 B
  __shared__ float    invl[BM];
  __shared__ unsigned maskl[BM][8];       // total LDS = 127488 B

  const int tid  = threadIdx.x;
  const int lane = tid & 63;
  const int wv   = tid >> 6;    // 0..7 -> 4x2 wave grid
  const int wm   = wv >> 1;     // wave row group (32 rows each)
  const int wn   = wv & 1;      // wave col group (128 cols each)
  const int l31  = lane & 31;
  const int hi   = lane >> 5;   // selects 8-k half of the 16-k step
  const long r0  = (long)blockIdx.x * BM;

  // ---- adjacency: per-row count + bitmask (4 threads per row) ----
  {
    const int r = tid >> 2, q = tid & 3;
    long rr = r0 + r; if (rr > NROWS - 1) rr = NROWS - 1;
    const int4* ap = (const int4*)(adj + rr * C_DIM + q * 64);
    unsigned w0 = 0, w1 = 0; int cnt = 0;
#pragma unroll
    for (int j = 0; j < 16; ++j) {
      int4 v = ap[j];
      unsigned b = (unsigned)((v.x > 0) | ((v.y > 0) << 1) |
                              ((v.z > 0) << 2) | ((v.w > 0) << 3));
      cnt += __popc(b);
      if (j < 8) w0 |= b << (j * 4); else w1 |= b << ((j - 8) * 4);
    }
    cnt += __shfl_xor(cnt, 1);   // 4 staging threads of a row are consecutive lanes
    cnt += __shfl_xor(cnt, 2);
    if (cnt == 0) { w0 = 0xffffffffu; w1 = 0xffffffffu; }  // softmax = 1/256
    maskl[r][q * 2]     = w0;
    maskl[r][q * 2 + 1] = w1;
    if (q == 0) invl[r] = (cnt > 0) ? (1.0f / (float)cnt) : (1.0f / 256.0f);
  }

  // ---- staging geometry ----
  const int sr = tid >> 2;            // row 0..127
  const int sq = tid & 3;             // 8-float k group
  long srow = r0 + sr; if (srow > NROWS - 1) srow = NROWS - 1;
  const float* xbase = X + srow * K_DIM + sq * 8;
  const int aoff = sr * LSTR + sq * 8;          // shorts; byte = sr*80+sq*16 (aligned)
  const __bf16* bsrc = (wv < 4) ? whi : wlo;    // waves 0-3 stage Bh, 4-7 stage Bl
  const int bwq = wv & 3;

  f32x16 acc[4];
#pragma unroll
  for (int n = 0; n < 4; ++n) acc[n] = (f32x16)(0.0f);

  f32x4 xa, xb;
  // ---- prologue: stage chunk 0 into buffer 0 ----
  {
    xa = *(const f32x4*)(xbase + 0);
    xb = *(const f32x4*)(xbase + 4);
    const char* s = (const char*)bsrc;
    char* dh = (char*)((wv < 4) ? Bh[0] : Bl[0]);
#pragma unroll
    for (int i = 0; i < 5; ++i) {
      int off = (bwq * 5 + i) * 1024;
      gload16(s + off + lane * 16, dh + off);
    }
    bf16x8 hv, lv;
#pragma unroll
    for (int e = 0; e < 4; ++e) {
      float f0 = xa[e], f1 = xb[e];
      __bf16 h0 = (__bf16)f0, h1 = (__bf16)f1;
      hv[e] = h0; hv[e + 4] = h1;
      lv[e] = (__bf16)(f0 - (float)h0);
      lv[e + 4] = (__bf16)(f1 - (float)h1);
    }
    *(bf16x8*)&Ah[0][aoff] = hv;
    *(bf16x8*)&Al[0][aoff] = lv;
  }
  __syncthreads();

  // ---- main 2-phase pipelined loop ----
  int cur = 0;
  for (int ck = 0; ck < NCHUNK; ++ck) {
    const bool pf = (ck + 1 < NCHUNK);
    if (pf) {
      // issue-early: X loads to regs, B global->LDS into other buffer
      xa = *(const f32x4*)(xbase + (ck + 1) * BK);
      xb = *(const f32x4*)(xbase + (ck + 1) * BK + 4);
      const char* s = (const char*)bsrc + (ck + 1) * CHUNK_BYTES;
      char* dh = (char*)((wv < 4) ? Bh[cur ^ 1] : Bl[cur ^ 1]);
#pragma unroll
      for (int i = 0; i < 5; ++i) {
        int off = (bwq * 5 + i) * 1024;
        gload16(s + off + lane * 16, dh + off);
      }
    }
    // compute current buffer
#pragma unroll
    for (int s2 = 0; s2 < 2; ++s2) {
      const int ko = s2 * 16 + hi * 8;
      bf16x8 ah = *(const bf16x8*)&Ah[cur][(wm * 32 + l31) * LSTR + ko];
      bf16x8 al = *(const bf16x8*)&Al[cur][(wm * 32 + l31) * LSTR + ko];
#pragma unroll
      for (int n = 0; n < 4; ++n) {
        const int coff = (wn * 128 + n * 32 + l31) * LSTR + ko;
        bf16x8 bh = *(const bf16x8*)&Bh[cur][coff];
        bf16x8 bl = *(const bf16x8*)&Bl[cur][coff];
        acc[n] = __builtin_amdgcn_mfma_f32_32x32x16_bf16(ah, bh, acc[n], 0, 0, 0);
        acc[n] = __builtin_amdgcn_mfma_f32_32x32x16_bf16(ah, bl, acc[n], 0, 0, 0);
        acc[n] = __builtin_amdgcn_mfma_f32_32x32x16_bf16(al, bh, acc[n], 0, 0, 0);
      }
    }
    if (pf) {
      // write-late: hi/lo split of next chunk's X into other buffer
      bf16x8 hv, lv;
#pragma unroll
      for (int e = 0; e < 4; ++e) {
        float f0 = xa[e], f1 = xb[e];
        __bf16 h0 = (__bf16)f0, h1 = (__bf16)f1;
        hv[e] = h0; hv[e + 4] = h1;
        lv[e] = (__bf16)(f0 - (float)h0);
        lv[e + 4] = (__bf16)(f1 - (float)h1);
      }
      *(bf16x8*)&Ah[cur ^ 1][aoff] = hv;
      *(bf16x8*)&Al[cur ^ 1][aoff] = lv;
    }
    __syncthreads();   // drains gloads (vmcnt) + ds_writes (lgkm) for next buf
    cur ^= 1;
  }

  // ---- fused epilogue: out = mask ? elu(h * inv) : 0 ----
  // C/D 32x32 layout: col = lane&31, row = (reg&3) + 8*(reg>>2) + 4*(lane>>5)
#pragma unroll
  for (int n = 0; n < 4; ++n) {
    const int col = wn * 128 + n * 32 + l31;
    const int mwi = col >> 5;   // wave-uniform
#pragma unroll
    for (int g = 0; g < 4; ++g) {
#pragma unroll
      for (int rb = 0; rb < 4; ++rb) {
        const int reg = g * 4 + rb;
        const int row = wm * 32 + rb + g * 8 + hi * 4;
        const long rr = r0 + row;
        if (rr < NROWS) {
          float inv = invl[row];
          unsigned mw = maskl[row][mwi];
          float h = acc[n][reg];
          float o = 0.0f;
          if ((mw >> (col & 31)) & 1u) {
            float hp = h * inv;
            o = hp > 0.0f ? hp : expm1f(hp);
          }
          out[rr * C_DIM + col] = o;
        }
      }
    }
  }
}

extern "C" void kernel_launch(void* const* d_in, const int* in_sizes, int n_in,
                              void* d_out, int out_size, void* d_ws, size_t ws_size,
                              hipStream_t stream) {
  const float* X   = (const float*)d_in[0];   // [200000,512] fp32
  const int*   adj = (const int*)d_in[1];     // [200000,256] int32
  const float* W   = (const float*)d_in[2];   // [512,256] fp32
  // d_in[3] (`a`) is mathematically unused (row-constant softmax cancels it).
  __bf16* whi = (__bf16*)d_ws;
  __bf16* wlo = (__bf16*)((char*)d_ws + WPACK_BYTES);  // 656KB of ws

  prep_w<<<512, 256, 0, stream>>>(W, whi, wlo);
  const int nblk = (NROWS + BM - 1) / BM;     // 1563, last block partial
  gat_kernel<<<nblk, 512, 0, stream>>>(X, adj, whi, wlo, (float*)d_out);
}